// Round 5
// baseline (28.146 us; speedup 1.0000x reference)
//
#include <hip/hip_runtime.h>

#define T_IN 2048
#define UPSCALE 480
#define T_OUT (T_IN * UPSCALE)   // 983040
#define BPB 64                    // blocks per batch
#define CHUNK (T_OUT / BPB)       // 15360 outputs per block
#define NTHREADS 256
#define ITERS (CHUNK / 4 / NTHREADS)  // 15 float4 groups per thread
#define NINTERVAL (T_IN - 1)      // 2047

__device__ __forceinline__ float signf(float x) {
    return (x > 0.f) ? 1.f : ((x < 0.f) ? -1.f : 0.f);
}

// Fritsch-Carlson edge slope (matches reference edge())
__device__ __forceinline__ float edge_slope(float dA, float dB) {
    float d = (3.f * dA - dB) * 0.5f;
    if (signf(d) != signf(dA)) {
        d = 0.f;
    } else if ((signf(dA) != signf(dB)) && (fabsf(d) > 3.f * fabsf(dA))) {
        d = 3.f * dA;
    }
    return d;
}

// Harmonic-mean interior slope with fast v_rcp_f32 (rel err ~1e-7).
// Safe: p>0 implies (a+b)^2 >= 4p (AM-GM), so rcp argument is well away
// from denormal/inf territory.
__device__ __forceinline__ float interior_slope_fast(float a, float b) {
    float p = a * b;
    float r = __builtin_amdgcn_rcpf(a + b);
    return (p > 0.f) ? 2.f * p * r : 0.f;
}

// Exact-division version for the edge blocks (matches reference bitwise-ish)
__device__ __forceinline__ float interior_slope(float a, float b) {
    float p = a * b;
    return (p > 0.f) ? (2.f * p / (a + b)) : 0.f;
}

__device__ __forceinline__ float4 eval_group(float c0, float c1, float c2, float c3,
                                             float s0, float step) {
    float4 r;
    float s = s0;
    r.x = __builtin_fmaf(__builtin_fmaf(__builtin_fmaf(c3, s, c2), s, c1), s, c0); s += step;
    r.y = __builtin_fmaf(__builtin_fmaf(__builtin_fmaf(c3, s, c2), s, c1), s, c0); s += step;
    r.z = __builtin_fmaf(__builtin_fmaf(__builtin_fmaf(c3, s, c2), s, c1), s, c0); s += step;
    r.w = __builtin_fmaf(__builtin_fmaf(__builtin_fmaf(c3, s, c2), s, c1), s, c0);
    return r;
}

__global__ __launch_bounds__(NTHREADS) void pchip_upsample_kernel(
    const float* __restrict__ x, float* __restrict__ out)
{
    const int b   = blockIdx.y;
    const int cb  = blockIdx.x;
    const int tid = threadIdx.x;

    const float STEP = (float)(T_IN - 1) / (float)(T_OUT - 1);
    const float* __restrict__ y = x + (size_t)b * T_IN;

    float4* outv = (float4*)(out + (size_t)b * T_OUT + (size_t)cb * CHUNK);
    const int jbase = cb * CHUNK;

    if (cb != 0 && cb != BPB - 1) {
        // FAST PATH (62/64 blocks): idx in [31, 2017] guaranteed ->
        // no clamps, no edge-slope handling, fast rcp slopes.
        #pragma unroll 5
        for (int it = 0; it < ITERS; ++it) {
            const int g  = it * NTHREADS + tid;
            const int j0 = jbase + g * 4;

            float t0 = (float)j0 * STEP;
            int idx = (int)t0;
            float s0 = t0 - (float)idx;

            float ym1 = y[idx - 1];
            float y0  = y[idx];
            float y1  = y[idx + 1];
            float y2  = y[idx + 2];

            float dl = y0 - ym1;
            float dc = y1 - y0;
            float dr = y2 - y1;

            float d0 = interior_slope_fast(dl, dc);
            float d1 = interior_slope_fast(dc, dr);

            float c0 = y0;
            float c1 = d0;
            float c2 = __builtin_fmaf(3.f, dc, -2.f * d0) - d1;
            float c3 = (d0 + d1) - 2.f * dc;

            outv[g] = eval_group(c0, c1, c2, c3, s0, STEP);
        }
    } else {
        // EDGE PATH (cb == 0 or 63): full clamping + Fritsch-Carlson edges.
        #pragma unroll 3
        for (int it = 0; it < ITERS; ++it) {
            const int g  = it * NTHREADS + tid;
            const int j0 = jbase + g * 4;

            float t0 = (float)j0 * STEP;
            int idx = (int)t0;
            idx = idx > (NINTERVAL - 1) ? (NINTERVAL - 1) : idx;
            float s0 = t0 - (float)idx;

            const int im1 = (idx > 0) ? idx - 1 : 0;
            const int ip2 = (idx < T_IN - 2) ? idx + 2 : T_IN - 1;

            float ym1 = y[im1];
            float y0  = y[idx];
            float y1  = y[idx + 1];
            float y2  = y[ip2];

            float dl = y0 - ym1;
            float dc = y1 - y0;
            float dr = y2 - y1;

            float d0 = interior_slope(dl, dc);
            if (idx == 0) d0 = edge_slope(dc, dr);
            float d1 = interior_slope(dc, dr);
            if (idx == NINTERVAL - 1) d1 = edge_slope(dc, dl);

            float c0 = y0;
            float c1 = d0;
            float c2 = __builtin_fmaf(3.f, dc, -2.f * d0) - d1;
            float c3 = (d0 + d1) - 2.f * dc;

            outv[g] = eval_group(c0, c1, c2, c3, s0, STEP);
        }
    }
}

extern "C" void kernel_launch(void* const* d_in, const int* in_sizes, int n_in,
                              void* d_out, int out_size, void* d_ws, size_t ws_size,
                              hipStream_t stream) {
    (void)d_ws; (void)ws_size; (void)n_in; (void)out_size;
    const float* x = (const float*)d_in[0];
    float* out = (float*)d_out;
    const int B = in_sizes[0] / T_IN;  // 32

    dim3 grid(BPB, B);
    pchip_upsample_kernel<<<grid, NTHREADS, 0, stream>>>(x, out);
}